// Round 2
// baseline (463.995 us; speedup 1.0000x reference)
//
#include <hip/hip_runtime.h>
#include <hip/hip_bf16.h>
#include <stdint.h>

typedef __attribute__((ext_vector_type(8))) short short8;
typedef __attribute__((ext_vector_type(4))) float f32x4;

#define NT 64        // K tiles of 64 (total K = 4096)
#define NBUF 4

typedef const __attribute__((address_space(1))) unsigned int* gas_ptr;
typedef __attribute__((address_space(3))) unsigned int* las_ptr;

__device__ __forceinline__ void gload_lds16(const void* g, void* l) {
  __builtin_amdgcn_global_load_lds((gas_ptr)g, (las_ptr)l, 16, 0, 0);
}

__device__ __forceinline__ unsigned pack_bf2(float a, float b) {
  union { __hip_bfloat162 h2; unsigned u; } cv;
  cv.h2 = __float22bfloat162_rn(make_float2(a, b));
  return cv.u;
}

__device__ __forceinline__ short8 pack8(const f32x4& a, const f32x4& b) {
  union { unsigned u[4]; short8 s; } cv;
  cv.u[0] = pack_bf2(a.x, a.y); cv.u[1] = pack_bf2(a.z, a.w);
  cv.u[2] = pack_bf2(b.x, b.y); cv.u[3] = pack_bf2(b.z, b.w);
  return cv.s;
}

// WB[n][kk] bf16, n = c*2 + (0:W1, 1:W2), kk = k*8 + e  (matches z window layout)
__global__ void pack_w(const float* __restrict__ W1, const float* __restrict__ W2,
                       __hip_bfloat16* __restrict__ WB) {
  int idx = blockIdx.x * 256 + threadIdx.x;   // 1<<20
  int kk = idx & 4095, n = idx >> 12;
  int k = kk >> 3, e = kk & 7, c = n >> 1;
  const float* W = (n & 1) ? W2 : W1;
  WB[(size_t)n * 4096 + kk] = __float2bfloat16(W[(c * 8 + e) * 512 + k]);
}

// Block: 64 rows x 128 cols, 4 waves (2M x 2N), wave tile 32x64.
// A: direct global fp32 -> bf16 in regs (prefetch 1 tile ahead).
// B: LDS 4-buffer ring via global_load_lds, issued 3 tiles ahead, raw s_barrier.
__global__ __launch_bounds__(256, 2) void gemm_gate(
    const float* __restrict__ z, const __hip_bfloat16* __restrict__ WB,
    const float* __restrict__ b1, const float* __restrict__ b2,
    float* __restrict__ partial) {
  __shared__ __align__(16) char Bs[NBUF][16384];   // 4 x 16KB = 64KB

  const int t = threadIdx.x;
  const int l = t & 63, w = t >> 6;      // 4 waves
  const int wm = w >> 1, wn = w & 1;
  const int lr = l & 15, lk = l >> 4;

  // XCD-chunked swizzle: HW bid h -> XCD h&7; give each XCD 64 consecutive
  // logicals so both N-halves of each M-tile co-reside on one XCD (z L2 reuse).
  const int h = blockIdx.x;
  const int logical = (h & 7) * 64 + (h >> 3);
  const int mb = logical >> 1, nh = logical & 1;

  const int rowbase = mb * 64 + wm * 32;
  const int nbase = nh * 128;

  // B staging: per thread 4 rounds, 16B each; LDS linear, source pre-swizzled.
  const char* bsrc[4];
#pragma unroll
  for (int r = 0; r < 4; ++r) {
    int col = r * 32 + (t >> 3);
    int inner = ((t & 7) * 16) ^ ((col & 7) << 4);
    bsrc[r] = (const char*)(WB + (size_t)(nbase + col) * 4096) + inner;
  }

  const char* abase = (const char*)(z + (size_t)(rowbase + lr) * 4096 + lk * 8);

  f32x4 acc[2][4];
#pragma unroll
  for (int i = 0; i < 2; ++i)
#pragma unroll
    for (int j = 0; j < 4; ++j) acc[i][j] = (f32x4)0.0f;

  f32x4 acur[8], anext[8];   // [mi*4 + ks*2 + hf]

  // ---- prologue: issue B(0..2), load A(0), drain, barrier
#pragma unroll
  for (int kt0 = 0; kt0 < 3; ++kt0)
#pragma unroll
    for (int r = 0; r < 4; ++r)
      gload_lds16(bsrc[r] + (size_t)kt0 * 128, &Bs[kt0][r * 4096 + t * 16]);
#pragma unroll
  for (int mi = 0; mi < 2; ++mi)
#pragma unroll
    for (int ks = 0; ks < 2; ++ks)
#pragma unroll
      for (int hf = 0; hf < 2; ++hf)
        acur[mi * 4 + ks * 2 + hf] =
            *(const f32x4*)(abase + ((size_t)mi * 16 * 4096 + ks * 32 + hf * 4) * 4);
  asm volatile("s_waitcnt vmcnt(0)" ::: "memory");
  __builtin_amdgcn_s_barrier();

  const int swz = (lr & 7) << 4;
#pragma unroll 1
  for (int kt = 0; kt < NT; ++kt) {
    // issue B(kt+3) into ring
    if (kt + 3 < NT) {
      char* dst = (char*)Bs[(kt + 3) & 3];
#pragma unroll
      for (int r = 0; r < 4; ++r)
        gload_lds16(bsrc[r] + (size_t)(kt + 3) * 128, dst + r * 4096 + t * 16);
    }
    // prefetch A(kt+1) to regs
    if (kt + 1 < NT) {
#pragma unroll
      for (int mi = 0; mi < 2; ++mi)
#pragma unroll
        for (int ks = 0; ks < 2; ++ks)
#pragma unroll
          for (int hf = 0; hf < 2; ++hf)
            anext[mi * 4 + ks * 2 + hf] = *(const f32x4*)(
                abase + ((size_t)(kt + 1) * 64 + (size_t)mi * 16 * 4096 + ks * 32 + hf * 4) * 4);
    }
    // cvt A(kt)  (compiler's counted vmcnt wait here also retires older B gloads)
    short8 af[2][2];
#pragma unroll
    for (int mi = 0; mi < 2; ++mi)
#pragma unroll
      for (int ks = 0; ks < 2; ++ks)
        af[mi][ks] = pack8(acur[mi * 4 + ks * 2], acur[mi * 4 + ks * 2 + 1]);
    // ds_read B frags (swizzled)
    const char* bb = (const char*)Bs[kt & 3];
    short8 bf[4][2];
#pragma unroll
    for (int nj = 0; nj < 4; ++nj) {
      const int col = wn * 64 + nj * 16 + lr;
#pragma unroll
      for (int ks = 0; ks < 2; ++ks)
        bf[nj][ks] = *(const short8*)(bb + col * 128 + ((ks * 64 + lk * 16) ^ swz));
    }
    // MFMA 2x4x2
#pragma unroll
    for (int mi = 0; mi < 2; ++mi)
#pragma unroll
      for (int nj = 0; nj < 4; ++nj)
#pragma unroll
        for (int ks = 0; ks < 2; ++ks)
          acc[mi][nj] = __builtin_amdgcn_mfma_f32_16x16x32_bf16(
              af[mi][ks], bf[nj][ks], acc[mi][nj], 0, 0, 0);
    if (kt + 1 < NT) {
#pragma unroll
      for (int i = 0; i < 8; ++i) acur[i] = anext[i];
    }
    __builtin_amdgcn_s_barrier();
  }

  // ---- epilogue: gate + max over this wave's 32 rows
  // C layout: col = lane&15, row = (lane>>4)*4 + reg
#pragma unroll
  for (int nj = 0; nj < 4; ++nj) {
    const int c = nh * 64 + wn * 32 + nj * 8 + (lr >> 1);
    const float vb1 = b1[c], vb2 = b2[c];
    float gm = -3.4e38f;
#pragma unroll
    for (int mi = 0; mi < 2; ++mi) {
#pragma unroll
      for (int rr = 0; rr < 4; ++rr) {
        float v = acc[mi][nj][rr];
        float p = __shfl_xor(v, 1, 64);
        float c1 = (lr & 1) ? p : v;
        float c2 = (lr & 1) ? v : p;
        c1 += vb1; c2 += vb2;
        float g = c1 * (1.0f / (1.0f + __expf(-c2)));
        gm = fmaxf(gm, g);
      }
    }
    gm = fmaxf(gm, __shfl_xor(gm, 16, 64));
    gm = fmaxf(gm, __shfl_xor(gm, 32, 64));
    if ((l < 16) && !(l & 1))
      partial[(size_t)(mb * 2 + wm) * 128 + c] = gm;
  }
}

// out[b][c] = max over 64 row-groups of 32 rows each
__global__ void reduce_max(const float* __restrict__ partial, float* __restrict__ out) {
  int idx = blockIdx.x * 256 + threadIdx.x;
  if (idx >= 1024) return;
  int b = idx >> 7, c = idx & 127;
  float m = -3.4e38f;
#pragma unroll 8
  for (int g = 0; g < 64; ++g)
    m = fmaxf(m, partial[(size_t)(b * 64 + g) * 128 + c]);
  out[idx] = m;
}

extern "C" void kernel_launch(void* const* d_in, const int* in_sizes, int n_in,
                              void* d_out, int out_size, void* d_ws, size_t ws_size,
                              hipStream_t stream) {
  const float* z  = (const float*)d_in[0];
  const float* W1 = (const float*)d_in[1];
  const float* b1 = (const float*)d_in[2];
  const float* W2 = (const float*)d_in[3];
  const float* b2 = (const float*)d_in[4];
  float* out = (float*)d_out;

  __hip_bfloat16* WB = (__hip_bfloat16*)d_ws;                    // 2 MB
  float* partial = (float*)((char*)d_ws + 2 * 1024 * 1024);      // 256 KB

  pack_w<<<4096, 256, 0, stream>>>(W1, W2, WB);
  gemm_gate<<<512, 256, 0, stream>>>(z, WB, b1, b2, partial);
  reduce_max<<<4, 256, 0, stream>>>(partial, out);
}